// Round 1
// baseline (686.681 us; speedup 1.0000x reference)
//
#include <hip/hip_runtime.h>
#include <math.h>

#define Bc 8
#define Nc 128
#define Dc 256
#define Hc 8
#define DKc 32

typedef __attribute__((ext_vector_type(8))) short short8;
typedef __attribute__((ext_vector_type(4))) float floatx4;

__device__ __forceinline__ unsigned short f2bf(float f) {
  unsigned int u = __float_as_uint(f);
  u += 0x7FFFu + ((u >> 16) & 1u);   // RNE to bf16 (inputs are normal floats)
  return (unsigned short)(u >> 16);
}

// ---------------------------------------------------------------------------
// cast fp32 -> bf16 (for Wk, Weo; 65536 elements each)
// ---------------------------------------------------------------------------
__global__ __launch_bounds__(256) void cast_bf16_kernel(
    const float* __restrict__ src, unsigned short* __restrict__ dst, int n) {
  const int i = (blockIdx.x * 256 + threadIdx.x) * 4;
  if (i < n) {
    const float4 v = *(const float4*)&src[i];
    *(ushort4*)&dst[i] = make_ushort4(f2bf(v.x), f2bf(v.y), f2bf(v.z), f2bf(v.w));
  }
}

// ---------------------------------------------------------------------------
// Small GEMM (fp32): C[M,256] = X @ W^T + b. 64x64 tile. q/v/node projections.
// ---------------------------------------------------------------------------
__global__ __launch_bounds__(256) void gemm_xwT_kernel(
    const float* __restrict__ X, const float* __restrict__ W,
    const float* __restrict__ bias, float* __restrict__ C, int M) {
  __shared__ float As[64][17];
  __shared__ float Ws[64][17];
  const int t = threadIdx.x;
  const int tx = t & 15;
  const int ty = t >> 4;
  const size_t row0 = (size_t)blockIdx.y * 64;
  const int col0 = blockIdx.x * 64;
  const int lr = t >> 2;
  const int lc = (t & 3) * 4;

  float acc[4][4] = {};

  for (int kk = 0; kk < 256; kk += 16) {
    float4 av = *(const float4*)&X[(row0 + lr) * 256 + kk + lc];
    float4 wv = *(const float4*)&W[(size_t)(col0 + lr) * 256 + kk + lc];
    As[lr][lc] = av.x; As[lr][lc + 1] = av.y; As[lr][lc + 2] = av.z; As[lr][lc + 3] = av.w;
    Ws[lr][lc] = wv.x; Ws[lr][lc + 1] = wv.y; Ws[lr][lc + 2] = wv.z; Ws[lr][lc + 3] = wv.w;
    __syncthreads();
#pragma unroll
    for (int e = 0; e < 16; ++e) {
      float a[4], w[4];
#pragma unroll
      for (int r = 0; r < 4; ++r) a[r] = As[ty * 4 + r][e];
#pragma unroll
      for (int c = 0; c < 4; ++c) w[c] = Ws[tx * 4 + c][e];
#pragma unroll
      for (int r = 0; r < 4; ++r)
#pragma unroll
        for (int c = 0; c < 4; ++c) acc[r][c] = fmaf(a[r], w[c], acc[r][c]);
    }
    __syncthreads();
  }

  const float4 bv = *(const float4*)&bias[col0 + tx * 4];
#pragma unroll
  for (int r = 0; r < 4; ++r) {
    float4 o;
    o.x = acc[r][0] + bv.x;
    o.y = acc[r][1] + bv.y;
    o.z = acc[r][2] + bv.z;
    o.w = acc[r][3] + bv.w;
    *(float4*)&C[(row0 + ty * 4 + r) * 256 + col0 + tx * 4] = o;
  }
}

// ---------------------------------------------------------------------------
// qw precompute: qw[bm,h,e] = sum_d q[bm,h*32+d]*Wk[h*32+d,e]   (fp32)
//                qb[bm,h]   = sum_d q[bm,h*32+d]*bk[h*32+d]
// Folds Wk into q so scores never need the materialized k tensor.
// ---------------------------------------------------------------------------
__global__ __launch_bounds__(256) void qw_kernel(
    const float* __restrict__ q, const float* __restrict__ Wk,
    const float* __restrict__ bk, float* __restrict__ qw,
    float* __restrict__ qb) {
  __shared__ float qs[256];
  const int bm = blockIdx.x;           // 0..1023
  const int e = threadIdx.x;           // 0..255
  qs[e] = q[(size_t)bm * 256 + e];
  __syncthreads();
  float acc[8] = {0.f, 0.f, 0.f, 0.f, 0.f, 0.f, 0.f, 0.f};
  for (int d = 0; d < 32; ++d) {
#pragma unroll
    for (int h = 0; h < 8; ++h)
      acc[h] = fmaf(qs[h * 32 + d], Wk[(size_t)(h * 32 + d) * 256 + e], acc[h]);
  }
#pragma unroll
  for (int h = 0; h < 8; ++h) qw[((size_t)bm * 8 + h) * 256 + e] = acc[h];
  if (e < 8) {
    float s = 0.f;
    for (int d = 0; d < 32; ++d) s = fmaf(qs[e * 32 + d], bk[e * 32 + d], s);
    qb[(size_t)bm * 8 + e] = s;
  }
}

// ---------------------------------------------------------------------------
// adjacency softmax (unchanged)
// ---------------------------------------------------------------------------
__global__ __launch_bounds__(128) void adj_softmax_kernel(
    const float* __restrict__ adj, const int* __restrict__ mask,
    const float* __restrict__ lam_p, float* __restrict__ adjs) {
  __shared__ float red[128];
  const int bi = blockIdx.x;
  const int b = bi >> 7;
  const int j = threadIdx.x;
  const float lam = lam_p[0];
  float x = (mask[b * 128 + j] != 0) ? (-lam * adj[(size_t)bi * 128 + j]) : -INFINITY;
  red[j] = x; __syncthreads();
  for (int s = 64; s > 0; s >>= 1) { if (j < s) red[j] = fmaxf(red[j], red[j + s]); __syncthreads(); }
  const float mx = red[0]; __syncthreads();
  const float e = expf(x - mx);
  red[j] = e; __syncthreads();
  for (int s = 64; s > 0; s >>= 1) { if (j < s) red[j] += red[j + s]; __syncthreads(); }
  const float z = red[0];
  adjs[(size_t)bi * 128 + j] = e / z;
}

// ---------------------------------------------------------------------------
// scores from key_edge directly (no k tensor), fully fp32:
//   out[b,h,m,n] = (qw[b,m,h,:].ke[b,m,n,:] + qb[b,m,h]) * inv_sqrt
//   in stored at isc[b,h,n,m] = (qw[b,n,h,:].ke[b,m,n,:] + qb[b,n,h]) * inv_sqrt
// Lane layout: h = lane>>3, s = lane&7 covers e-slice s*32..s*32+31.
// Block handles an m-pair (M_B=2) so qw[b,n] is loaded once per 2 ke rows.
// XCD-chunked swizzle keeps one batch b per XCD -> qw[b] (1MB) L2-resident.
// ---------------------------------------------------------------------------
__global__ __launch_bounds__(256) void scores_qw_kernel(
    const float* __restrict__ ke, const float* __restrict__ qw,
    const float* __restrict__ qb, float* __restrict__ osc,
    float* __restrict__ isc) {
  const int bid = blockIdx.x;                    // 0..511
  const int swz = (bid & 7) * 64 + (bid >> 3);   // bijective (512 % 8 == 0)
  const int b = swz >> 6;
  const int m0 = (swz & 63) * 2;
  const int lane = threadIdx.x & 63;
  const int wave = threadIdx.x >> 6;
  const int h = lane >> 3, s = lane & 7;
  const float inv_sqrt = 0.17677669529663687f;

  float4 qma[8], qmb[8];
  const size_t qbase0 = (((size_t)(b * 128 + m0)) * 8 + h) * 256 + s * 32;
  const size_t qbase1 = qbase0 + 8 * 256;
#pragma unroll
  for (int f = 0; f < 8; ++f) {
    qma[f] = *(const float4*)&qw[qbase0 + f * 4];
    qmb[f] = *(const float4*)&qw[qbase1 + f * 4];
  }
  const float qbm0 = qb[(size_t)(b * 128 + m0) * 8 + h];
  const float qbm1 = qb[(size_t)(b * 128 + m0 + 1) * 8 + h];

  for (int n = wave; n < 128; n += 4) {
    const size_t kr0 = (((size_t)(b * 128 + m0)) * 128 + n) * 256 + s * 32;
    const size_t kr1 = kr0 + 128 * 256;
    const size_t qnb = (((size_t)(b * 128 + n)) * 8 + h) * 256 + s * 32;
    float po0 = 0.f, po1 = 0.f, pi0 = 0.f, pi1 = 0.f;
#pragma unroll
    for (int f = 0; f < 8; ++f) {
      const float4 k0 = *(const float4*)&ke[kr0 + f * 4];
      const float4 k1 = *(const float4*)&ke[kr1 + f * 4];
      const float4 qn = *(const float4*)&qw[qnb + f * 4];
      po0 = fmaf(k0.x, qma[f].x, fmaf(k0.y, qma[f].y, fmaf(k0.z, qma[f].z, fmaf(k0.w, qma[f].w, po0))));
      po1 = fmaf(k1.x, qmb[f].x, fmaf(k1.y, qmb[f].y, fmaf(k1.z, qmb[f].z, fmaf(k1.w, qmb[f].w, po1))));
      pi0 = fmaf(k0.x, qn.x, fmaf(k0.y, qn.y, fmaf(k0.z, qn.z, fmaf(k0.w, qn.w, pi0))));
      pi1 = fmaf(k1.x, qn.x, fmaf(k1.y, qn.y, fmaf(k1.z, qn.z, fmaf(k1.w, qn.w, pi1))));
    }
#pragma unroll
    for (int off = 1; off < 8; off <<= 1) {
      po0 += __shfl_xor(po0, off, 64);
      po1 += __shfl_xor(po1, off, 64);
      pi0 += __shfl_xor(pi0, off, 64);
      pi1 += __shfl_xor(pi1, off, 64);
    }
    if (s == 0) {
      const float qbn = qb[(size_t)(b * 128 + n) * 8 + h];
      const size_t hb = (size_t)(b * 8 + h) * 128;
      osc[(hb + m0) * 128 + n]     = (po0 + qbm0) * inv_sqrt;
      osc[(hb + m0 + 1) * 128 + n] = (po1 + qbm1) * inv_sqrt;
      isc[(hb + n) * 128 + m0]     = (pi0 + qbn) * inv_sqrt;
      isc[(hb + n) * 128 + m0 + 1] = (pi1 + qbn) * inv_sqrt;
    }
  }
}

// ---------------------------------------------------------------------------
// message (unchanged)
// ---------------------------------------------------------------------------
__global__ __launch_bounds__(128) void message_kernel(
    const float* __restrict__ osc, const float* __restrict__ isc,
    const float* __restrict__ adjs, const int* __restrict__ mask,
    float* __restrict__ msg) {
  __shared__ float red[128];
  const int bhi = blockIdx.x;
  const int i = bhi & 127;
  const int b = bhi >> 10;
  const int j = threadIdx.x;
  const bool mj = mask[b * 128 + j] != 0;

  const float so = mj ? osc[(size_t)bhi * 128 + j] : -INFINITY;
  const float si = mj ? isc[(size_t)bhi * 128 + j] : -INFINITY;

  red[j] = so; __syncthreads();
  for (int s = 64; s > 0; s >>= 1) { if (j < s) red[j] = fmaxf(red[j], red[j + s]); __syncthreads(); }
  const float mo = red[0]; __syncthreads();
  const float eo = expf(so - mo);
  red[j] = eo; __syncthreads();
  for (int s = 64; s > 0; s >>= 1) { if (j < s) red[j] += red[j + s]; __syncthreads(); }
  const float zo = red[0]; __syncthreads();
  const float oa = eo / zo;

  red[j] = si; __syncthreads();
  for (int s = 64; s > 0; s >>= 1) { if (j < s) red[j] = fmaxf(red[j], red[j + s]); __syncthreads(); }
  const float mi = red[0]; __syncthreads();
  const float ei = expf(si - mi);
  red[j] = ei; __syncthreads();
  for (int s = 64; s > 0; s >>= 1) { if (j < s) red[j] += red[j + s]; __syncthreads(); }
  const float zi = red[0];
  const float ia = ei / zi;

  float val = oa + ia - ((i == j) ? oa : 0.0f);
  val *= adjs[((size_t)(b * 128 + i)) * 128 + j];
  msg[(size_t)bhi * 128 + j] = val;
}

// ---------------------------------------------------------------------------
// node_hidden (unchanged)
// ---------------------------------------------------------------------------
__global__ __launch_bounds__(256) void node_hidden_kernel(
    const float* __restrict__ msg, const float* __restrict__ v,
    float* __restrict__ nh) {
  __shared__ float Ms[32][129];
  __shared__ float Vs[128][33];
  const int blk = blockIdx.x;
  const int mblk = blk & 3;
  const int bh = blk >> 2;
  const int h = bh & 7;
  const int b = bh >> 3;
  const int t = threadIdx.x;

  {
    const int n = t & 127, r0 = t >> 7;
#pragma unroll
    for (int p = 0; p < 16; ++p) {
      const int r = r0 + p * 2;
      Ms[r][n] = msg[((size_t)bh * 128 + mblk * 32 + r) * 128 + n];
    }
  }
  {
    const int dk = t & 31, n0 = t >> 5;
#pragma unroll
    for (int p = 0; p < 16; ++p) {
      const int n = n0 + p * 8;
      Vs[n][dk] = v[((size_t)b * 128 + n) * 256 + h * 32 + dk];
    }
  }
  __syncthreads();

  const int dk = t & 31;
  const int mg = t >> 5;
  float acc[4] = {0.f, 0.f, 0.f, 0.f};
  for (int n = 0; n < 128; ++n) {
    const float vv = Vs[n][dk];
#pragma unroll
    for (int r = 0; r < 4; ++r) acc[r] = fmaf(Ms[mg + 8 * r][n], vv, acc[r]);
  }
#pragma unroll
  for (int r = 0; r < 4; ++r) {
    const int m = mblk * 32 + mg + 8 * r;
    nh[((size_t)b * 128 + m) * 256 + h * 32 + dk] = acc[r];
  }
}

// ---------------------------------------------------------------------------
// Fused edge: out = bf16( (ke@Wk^T + bk) .* msg ) @ Weo^T + beo, never
// materializing k. Block = 64 edge rows x 256 cols, two chained MFMA phases
// through an LDS bf16 intermediate K1[64][264].
// Both phases use swapped mfma(Wfrag, kefrag) -> transposed D so each lane
// holds 4 CONSECUTIVE output columns: ds_write_b64 into K1, float4 stores out.
// ---------------------------------------------------------------------------
__global__ __launch_bounds__(256) void edge_fused_kernel(
    const float* __restrict__ ke, const float* __restrict__ msg,
    const unsigned short* __restrict__ wk, const unsigned short* __restrict__ weo,
    const float* __restrict__ bk, const float* __restrict__ beo,
    float* __restrict__ out) {
  __shared__ __align__(16) unsigned short As[64 * 40];     //  5120 B
  __shared__ __align__(16) unsigned short Ws[256 * 40];    // 20480 B (Wk then Weo)
  __shared__ __align__(16) unsigned short K1[64 * 264];    // 33792 B intermediate
  __shared__ float Msgs[64][8];
  const int nblk = blockIdx.x;          // 0..1
  const int bm = blockIdx.y;            // 0..1023
  const int b = bm >> 7;
  const int m = bm & 127;
  const int n0 = nblk * 64;
  const int t = threadIdx.x;
  const int l = t & 63;
  const int w = t >> 6;                 // wave -> col group of 64
  const int lr = l & 15;
  const int lk = l >> 4;
  const size_t rowbase = ((size_t)bm * 128 + n0) * 256;

  // stage msg for these 64 rows x 8 heads
#pragma unroll
  for (int p = 0; p < 2; ++p) {
    const int idx = t + p * 256;
    const int r = idx >> 3, h = idx & 7;
    Msgs[r][h] = msg[(((size_t)(b * 8 + h) * 128 + m) * 128) + n0 + r];
  }

  floatx4 acc[4][4] = {};

  // -------- phase A: K1 = bf16( (ke @ Wk^T + bk) .* msg ) ----------------
  for (int kk = 0; kk < 256; kk += 32) {
    float4 av[2]; int arow[2], akc[2];
#pragma unroll
    for (int p = 0; p < 2; ++p) {
      const int f = p * 256 + t;
      arow[p] = f >> 3; akc[p] = (f & 7) * 4;
      av[p] = *(const float4*)&ke[rowbase + (size_t)arow[p] * 256 + kk + akc[p]];
    }
    uint4 wv[4];
#pragma unroll
    for (int p = 0; p < 4; ++p) {
      const int f = p * 256 + t;
      const int row = f >> 2, kc = (f & 3) * 8;
      wv[p] = *(const uint4*)&wk[(size_t)row * 256 + kk + kc];
    }
    __syncthreads();  // previous iteration's frag reads done (iter0: Msgs done)
#pragma unroll
    for (int p = 0; p < 2; ++p)
      *(ushort4*)&As[arow[p] * 40 + akc[p]] =
          make_ushort4(f2bf(av[p].x), f2bf(av[p].y), f2bf(av[p].z), f2bf(av[p].w));
#pragma unroll
    for (int p = 0; p < 4; ++p) {
      const int f = p * 256 + t;
      const int row = f >> 2, kc = (f & 3) * 8;
      *(uint4*)&Ws[row * 40 + kc] = wv[p];
    }
    __syncthreads();
    short8 a[4], bw[4];
#pragma unroll
    for (int i = 0; i < 4; ++i)
      a[i] = *(const short8*)&As[(i * 16 + lr) * 40 + lk * 8];
#pragma unroll
    for (int j = 0; j < 4; ++j)
      bw[j] = *(const short8*)&Ws[(w * 64 + j * 16 + lr) * 40 + lk * 8];
#pragma unroll
    for (int i = 0; i < 4; ++i)
#pragma unroll
      for (int j = 0; j < 4; ++j)   // swapped operands -> lane holds 4 consecutive cols
        acc[i][j] = __builtin_amdgcn_mfma_f32_16x16x32_bf16(bw[j], a[i], acc[i][j], 0, 0, 0);
  }

  // bias + per-head msg scale, pack bf16, ds_write_b64 to K1
#pragma unroll
  for (int j = 0; j < 4; ++j) {
    const int col = w * 64 + j * 16 + lk * 4;          // k-output dim o
    const float4 kb = *(const float4*)&bk[col];
    const int h = col >> 5;
#pragma unroll
    for (int i = 0; i < 4; ++i) {
      const int row = i * 16 + lr;                     // n-offset within tile
      const float sc = Msgs[row][h];
      *(ushort4*)&K1[row * 264 + col] = make_ushort4(
          f2bf((acc[i][j][0] + kb.x) * sc), f2bf((acc[i][j][1] + kb.y) * sc),
          f2bf((acc[i][j][2] + kb.z) * sc), f2bf((acc[i][j][3] + kb.w) * sc));
      acc[i][j] = (floatx4){0.f, 0.f, 0.f, 0.f};       // reuse for phase B
    }
  }
  __syncthreads();  // K1 complete; all phase-A Ws reads done

  // -------- phase B: out = K1 @ Weo^T + beo ------------------------------
  for (int kk = 0; kk < 256; kk += 32) {
    uint4 wv[4];
#pragma unroll
    for (int p = 0; p < 4; ++p) {
      const int f = p * 256 + t;
      const int row = f >> 2, kc = (f & 3) * 8;
      wv[p] = *(const uint4*)&weo[(size_t)row * 256 + kk + kc];
    }
    __syncthreads();  // previous iteration's frag reads done
#pragma unroll
    for (int p = 0; p < 4; ++p) {
      const int f = p * 256 + t;
      const int row = f >> 2, kc = (f & 3) * 8;
      *(uint4*)&Ws[row * 40 + kc] = wv[p];
    }
    __syncthreads();
    short8 ak[4], bw[4];
#pragma unroll
    for (int i = 0; i < 4; ++i)
      ak[i] = *(const short8*)&K1[(i * 16 + lr) * 264 + kk + lk * 8];
#pragma unroll
    for (int j = 0; j < 4; ++j)
      bw[j] = *(const short8*)&Ws[(w * 64 + j * 16 + lr) * 40 + lk * 8];
#pragma unroll
    for (int i = 0; i < 4; ++i)
#pragma unroll
      for (int j = 0; j < 4; ++j)
        acc[i][j] = __builtin_amdgcn_mfma_f32_16x16x32_bf16(bw[j], ak[i], acc[i][j], 0, 0, 0);
  }

  // epilogue: lane holds OUT[row=i*16+lr][col=w*64+j*16+lk*4 .. +3] -> float4
  float4 bj[4];
#pragma unroll
  for (int j = 0; j < 4; ++j) bj[j] = *(const float4*)&beo[w * 64 + j * 16 + lk * 4];
#pragma unroll
  for (int i = 0; i < 4; ++i) {
    const size_t rb = rowbase + (size_t)(i * 16 + lr) * 256;
#pragma unroll
    for (int j = 0; j < 4; ++j) {
      float4 o;
      o.x = acc[i][j][0] + bj[j].x;
      o.y = acc[i][j][1] + bj[j].y;
      o.z = acc[i][j][2] + bj[j].z;
      o.w = acc[i][j][3] + bj[j].w;
      *(float4*)&out[rb + w * 64 + j * 16 + lk * 4] = o;
    }
  }
}

// ---------------------------------------------------------------------------
extern "C" void kernel_launch(void* const* d_in, const int* in_sizes, int n_in,
                              void* d_out, int out_size, void* d_ws, size_t ws_size,
                              hipStream_t stream) {
  (void)in_sizes; (void)n_in; (void)out_size; (void)ws_size;
  const float* query_node = (const float*)d_in[0];
  const float* value_node = (const float*)d_in[1];
  const float* key_edge   = (const float*)d_in[2];
  const float* adj_matrix = (const float*)d_in[3];
  const int*   mask       = (const int*)d_in[4];
  const float* Wq  = (const float*)d_in[5];
  const float* bq  = (const float*)d_in[6];
  const float* Wk  = (const float*)d_in[7];
  const float* bk  = (const float*)d_in[8];
  const float* Wv  = (const float*)d_in[9];
  const float* bv  = (const float*)d_in[10];
  const float* Wno = (const float*)d_in[11];
  const float* bno = (const float*)d_in[12];
  const float* Weo = (const float*)d_in[13];
  const float* beo = (const float*)d_in[14];
  const float* lam = (const float*)d_in[15];

  float* out = (float*)d_out;
  float* node_out = out;                                  // [B,N,D]
  float* edge_out = out + (size_t)Bc * Nc * Dc;           // [B,N,N,D]

  float* ws = (float*)d_ws;
  float* q    = ws; ws += (size_t)Bc * Nc * Dc;
  float* v    = ws; ws += (size_t)Bc * Nc * Dc;
  float* adjs = ws; ws += (size_t)Bc * Nc * Nc;
  float* osc  = ws; ws += (size_t)Bc * Hc * Nc * Nc;
  float* isc  = ws; ws += (size_t)Bc * Hc * Nc * Nc;
  float* msg  = ws; ws += (size_t)Bc * Hc * Nc * Nc;
  float* nh   = ws; ws += (size_t)Bc * Nc * Dc;
  float* qw   = ws; ws += (size_t)Bc * Nc * Hc * Dc;      // 8 MB
  float* qb   = ws; ws += (size_t)Bc * Nc * Hc;
  unsigned short* wkbf  = (unsigned short*)ws; ws += 32768;   // 65536 bf16
  unsigned short* weobf = (unsigned short*)ws; ws += 32768;   // 65536 bf16

  // pre-cast weights to bf16 (edge kernel inputs)
  cast_bf16_kernel<<<dim3(64), 256, 0, stream>>>(Wk, wkbf, Dc * Dc);
  cast_bf16_kernel<<<dim3(64), 256, 0, stream>>>(Weo, weobf, Dc * Dc);
  // q, v projections (fp32, small)
  gemm_xwT_kernel<<<dim3(4, 16), 256, 0, stream>>>(query_node, Wq, bq, q, Bc * Nc);
  gemm_xwT_kernel<<<dim3(4, 16), 256, 0, stream>>>(value_node, Wv, bv, v, Bc * Nc);
  // fold Wk/bk into q (fp32) -> qw, qb
  qw_kernel<<<dim3(Bc * Nc), 256, 0, stream>>>(q, Wk, bk, qw, qb);
  // adjacency softmax
  adj_softmax_kernel<<<dim3(Bc * Nc), 128, 0, stream>>>(adj_matrix, mask, lam, adjs);
  // attention scores straight from key_edge (first 134MB reader; warms L3)
  scores_qw_kernel<<<dim3(512), 256, 0, stream>>>(key_edge, qw, qb, osc, isc);
  // softmaxes + message
  message_kernel<<<dim3(Bc * Hc * Nc), 128, 0, stream>>>(osc, isc, adjs, mask, msg);
  // node hidden + node projection (fp32)
  node_hidden_kernel<<<dim3(Bc * Hc * 4), 256, 0, stream>>>(msg, v, nh);
  gemm_xwT_kernel<<<dim3(4, 16), 256, 0, stream>>>(nh, Wno, bno, node_out, Bc * Nc);
  // fused edge pipeline: ke -> k -> msg-scale -> Weo projection (one pass)
  edge_fused_kernel<<<dim3(2, 1024), 256, 0, stream>>>(
      key_edge, msg, wkbf, weobf, bk, beo, edge_out);
}

// Round 3
// 579.544 us; speedup vs baseline: 1.1849x; 1.1849x over previous
//
#include <hip/hip_runtime.h>
#include <math.h>

#define Bc 8
#define Nc 128
#define Dc 256
#define Hc 8
#define DKc 32

typedef __attribute__((ext_vector_type(8))) short short8;
typedef __attribute__((ext_vector_type(4))) float floatx4;

__device__ __forceinline__ unsigned short f2bf(float f) {
  unsigned int u = __float_as_uint(f);
  u += 0x7FFFu + ((u >> 16) & 1u);   // RNE to bf16 (inputs are normal floats)
  return (unsigned short)(u >> 16);
}

// ---------------------------------------------------------------------------
// cast fp32 -> bf16 (for Wk, Weo; 65536 elements each)
// ---------------------------------------------------------------------------
__global__ __launch_bounds__(256) void cast_bf16_kernel(
    const float* __restrict__ src, unsigned short* __restrict__ dst, int n) {
  const int i = (blockIdx.x * 256 + threadIdx.x) * 4;
  if (i < n) {
    const float4 v = *(const float4*)&src[i];
    *(ushort4*)&dst[i] = make_ushort4(f2bf(v.x), f2bf(v.y), f2bf(v.z), f2bf(v.w));
  }
}

// ---------------------------------------------------------------------------
// Small GEMM (fp32): C[M,256] = X @ W^T + b. 64x64 tile. q/v/node projections.
// ---------------------------------------------------------------------------
__global__ __launch_bounds__(256) void gemm_xwT_kernel(
    const float* __restrict__ X, const float* __restrict__ W,
    const float* __restrict__ bias, float* __restrict__ C, int M) {
  __shared__ float As[64][17];
  __shared__ float Ws[64][17];
  const int t = threadIdx.x;
  const int tx = t & 15;
  const int ty = t >> 4;
  const size_t row0 = (size_t)blockIdx.y * 64;
  const int col0 = blockIdx.x * 64;
  const int lr = t >> 2;
  const int lc = (t & 3) * 4;

  float acc[4][4] = {};

  for (int kk = 0; kk < 256; kk += 16) {
    float4 av = *(const float4*)&X[(row0 + lr) * 256 + kk + lc];
    float4 wv = *(const float4*)&W[(size_t)(col0 + lr) * 256 + kk + lc];
    As[lr][lc] = av.x; As[lr][lc + 1] = av.y; As[lr][lc + 2] = av.z; As[lr][lc + 3] = av.w;
    Ws[lr][lc] = wv.x; Ws[lr][lc + 1] = wv.y; Ws[lr][lc + 2] = wv.z; Ws[lr][lc + 3] = wv.w;
    __syncthreads();
#pragma unroll
    for (int e = 0; e < 16; ++e) {
      float a[4], w[4];
#pragma unroll
      for (int r = 0; r < 4; ++r) a[r] = As[ty * 4 + r][e];
#pragma unroll
      for (int c = 0; c < 4; ++c) w[c] = Ws[tx * 4 + c][e];
#pragma unroll
      for (int r = 0; r < 4; ++r)
#pragma unroll
        for (int c = 0; c < 4; ++c) acc[r][c] = fmaf(a[r], w[c], acc[r][c]);
    }
    __syncthreads();
  }

  const float4 bv = *(const float4*)&bias[col0 + tx * 4];
#pragma unroll
  for (int r = 0; r < 4; ++r) {
    float4 o;
    o.x = acc[r][0] + bv.x;
    o.y = acc[r][1] + bv.y;
    o.z = acc[r][2] + bv.z;
    o.w = acc[r][3] + bv.w;
    *(float4*)&C[(row0 + ty * 4 + r) * 256 + col0 + tx * 4] = o;
  }
}

// ---------------------------------------------------------------------------
// adjacency softmax (unchanged)
// ---------------------------------------------------------------------------
__global__ __launch_bounds__(128) void adj_softmax_kernel(
    const float* __restrict__ adj, const int* __restrict__ mask,
    const float* __restrict__ lam_p, float* __restrict__ adjs) {
  __shared__ float red[128];
  const int bi = blockIdx.x;
  const int b = bi >> 7;
  const int j = threadIdx.x;
  const float lam = lam_p[0];
  float x = (mask[b * 128 + j] != 0) ? (-lam * adj[(size_t)bi * 128 + j]) : -INFINITY;
  red[j] = x; __syncthreads();
  for (int s = 64; s > 0; s >>= 1) { if (j < s) red[j] = fmaxf(red[j], red[j + s]); __syncthreads(); }
  const float mx = red[0]; __syncthreads();
  const float e = expf(x - mx);
  red[j] = e; __syncthreads();
  for (int s = 64; s > 0; s >>= 1) { if (j < s) red[j] += red[j + s]; __syncthreads(); }
  const float z = red[0];
  adjs[(size_t)bi * 128 + j] = e / z;
}

// ---------------------------------------------------------------------------
// kscore: compute k-tile (64 edge rows x 256 k-dims) via bf16 MFMA from
// key_edge, then BOTH score tensors straight from the accumulators:
//   osc[b,h,m,n] = inv_sqrt * sum_d q[b,m,h*32+d] * K[n, h*32+d]
//   isc[b,h,n,m] = inv_sqrt * sum_d q[b,n,h*32+d] * K[n, h*32+d]
// k (with bk) never touches HBM. Swapped mfma(Wfrag, kefrag): lane holds
// rows i*16+lr, cols w*64+j*16+lk*4+r (4 consecutive k-dims). Cols of one
// wave span exactly heads {2w, 2w+1}; per-(row,head) sums finish with
// shfl_xor over the 4 lk-lanes.
// ---------------------------------------------------------------------------
__global__ __launch_bounds__(256) void kscore_kernel(
    const float* __restrict__ ke, const float* __restrict__ q,
    const unsigned short* __restrict__ wk, const float* __restrict__ bk,
    float* __restrict__ osc, float* __restrict__ isc) {
  __shared__ __align__(16) unsigned short As[64 * 40];     //  5120 B
  __shared__ __align__(16) unsigned short Ws[256 * 40];    // 20480 B
  const int nblk = blockIdx.x;          // 0..1
  const int bm = blockIdx.y;            // 0..1023
  const int b = bm >> 7;
  const int m = bm & 127;
  const int n0 = nblk * 64;
  const int t = threadIdx.x;
  const int l = t & 63;
  const int w = t >> 6;                 // wave -> k-col group of 64 (heads 2w,2w+1)
  const int lr = l & 15;
  const int lk = l >> 4;
  const size_t rowbase = ((size_t)bm * 128 + n0) * 256;

  floatx4 acc[4][4] = {};

  for (int kk = 0; kk < 256; kk += 32) {
    float4 av[2]; int arow[2], akc[2];
#pragma unroll
    for (int p = 0; p < 2; ++p) {
      const int f = p * 256 + t;
      arow[p] = f >> 3; akc[p] = (f & 7) * 4;
      av[p] = *(const float4*)&ke[rowbase + (size_t)arow[p] * 256 + kk + akc[p]];
    }
    uint4 wv[4];
#pragma unroll
    for (int p = 0; p < 4; ++p) {
      const int f = p * 256 + t;
      const int row = f >> 2, kc = (f & 3) * 8;
      wv[p] = *(const uint4*)&wk[(size_t)row * 256 + kk + kc];
    }
    __syncthreads();  // previous iteration's frag reads done
#pragma unroll
    for (int p = 0; p < 2; ++p)
      *(ushort4*)&As[arow[p] * 40 + akc[p]] =
          make_ushort4(f2bf(av[p].x), f2bf(av[p].y), f2bf(av[p].z), f2bf(av[p].w));
#pragma unroll
    for (int p = 0; p < 4; ++p) {
      const int f = p * 256 + t;
      const int row = f >> 2, kc = (f & 3) * 8;
      *(uint4*)&Ws[row * 40 + kc] = wv[p];
    }
    __syncthreads();
    short8 a[4], bw[4];
#pragma unroll
    for (int i = 0; i < 4; ++i)
      a[i] = *(const short8*)&As[(i * 16 + lr) * 40 + lk * 8];
#pragma unroll
    for (int j = 0; j < 4; ++j)
      bw[j] = *(const short8*)&Ws[(w * 64 + j * 16 + lr) * 40 + lk * 8];
#pragma unroll
    for (int i = 0; i < 4; ++i)
#pragma unroll
      for (int j = 0; j < 4; ++j)   // swapped -> lane holds 4 consecutive k-cols
        acc[i][j] = __builtin_amdgcn_mfma_f32_16x16x32_bf16(bw[j], a[i], acc[i][j], 0, 0, 0);
  }

  const float inv_sqrt = 0.17677669529663687f;
  float4 qm4[4], kb4[4];
#pragma unroll
  for (int j = 0; j < 4; ++j) {
    qm4[j] = *(const float4*)&q[((size_t)(b * 128 + m)) * 256 + w * 64 + j * 16 + lk * 4];
    kb4[j] = *(const float4*)&bk[w * 64 + j * 16 + lk * 4];
  }
#pragma unroll
  for (int i = 0; i < 4; ++i) {
    const int ng = n0 + i * 16 + lr;
    const size_t qnb = ((size_t)(b * 128 + ng)) * 256 + w * 64 + lk * 4;
    float po0 = 0.f, po1 = 0.f, pi0 = 0.f, pi1 = 0.f;
#pragma unroll
    for (int j = 0; j < 4; ++j) {
      const float4 qn = *(const float4*)&q[qnb + j * 16];
      const float k0 = acc[i][j][0] + kb4[j].x;
      const float k1 = acc[i][j][1] + kb4[j].y;
      const float k2 = acc[i][j][2] + kb4[j].z;
      const float k3 = acc[i][j][3] + kb4[j].w;
      const float so = fmaf(k0, qm4[j].x, fmaf(k1, qm4[j].y, fmaf(k2, qm4[j].z, k3 * qm4[j].w)));
      const float si = fmaf(k0, qn.x, fmaf(k1, qn.y, fmaf(k2, qn.z, k3 * qn.w)));
      if (j < 2) { po0 += so; pi0 += si; } else { po1 += so; pi1 += si; }
    }
    po0 += __shfl_xor(po0, 16, 64); po0 += __shfl_xor(po0, 32, 64);
    po1 += __shfl_xor(po1, 16, 64); po1 += __shfl_xor(po1, 32, 64);
    pi0 += __shfl_xor(pi0, 16, 64); pi0 += __shfl_xor(pi0, 32, 64);
    pi1 += __shfl_xor(pi1, 16, 64); pi1 += __shfl_xor(pi1, 32, 64);
    if (lk == 0) {
      const int h0 = w * 2, h1 = w * 2 + 1;
      osc[((size_t)(b * 8 + h0) * 128 + m) * 128 + ng] = po0 * inv_sqrt;
      osc[((size_t)(b * 8 + h1) * 128 + m) * 128 + ng] = po1 * inv_sqrt;
      isc[((size_t)(b * 8 + h0) * 128 + ng) * 128 + m] = pi0 * inv_sqrt;
      isc[((size_t)(b * 8 + h1) * 128 + ng) * 128 + m] = pi1 * inv_sqrt;
    }
  }
}

// ---------------------------------------------------------------------------
// message (unchanged)
// ---------------------------------------------------------------------------
__global__ __launch_bounds__(128) void message_kernel(
    const float* __restrict__ osc, const float* __restrict__ isc,
    const float* __restrict__ adjs, const int* __restrict__ mask,
    float* __restrict__ msg) {
  __shared__ float red[128];
  const int bhi = blockIdx.x;
  const int i = bhi & 127;
  const int b = bhi >> 10;
  const int j = threadIdx.x;
  const bool mj = mask[b * 128 + j] != 0;

  const float so = mj ? osc[(size_t)bhi * 128 + j] : -INFINITY;
  const float si = mj ? isc[(size_t)bhi * 128 + j] : -INFINITY;

  red[j] = so; __syncthreads();
  for (int s = 64; s > 0; s >>= 1) { if (j < s) red[j] = fmaxf(red[j], red[j + s]); __syncthreads(); }
  const float mo = red[0]; __syncthreads();
  const float eo = expf(so - mo);
  red[j] = eo; __syncthreads();
  for (int s = 64; s > 0; s >>= 1) { if (j < s) red[j] += red[j + s]; __syncthreads(); }
  const float zo = red[0]; __syncthreads();
  const float oa = eo / zo;

  red[j] = si; __syncthreads();
  for (int s = 64; s > 0; s >>= 1) { if (j < s) red[j] = fmaxf(red[j], red[j + s]); __syncthreads(); }
  const float mi = red[0]; __syncthreads();
  const float ei = expf(si - mi);
  red[j] = ei; __syncthreads();
  for (int s = 64; s > 0; s >>= 1) { if (j < s) red[j] += red[j + s]; __syncthreads(); }
  const float zi = red[0];
  const float ia = ei / zi;

  float val = oa + ia - ((i == j) ? oa : 0.0f);
  val *= adjs[((size_t)(b * 128 + i)) * 128 + j];
  msg[(size_t)bhi * 128 + j] = val;
}

// ---------------------------------------------------------------------------
// node_hidden (unchanged)
// ---------------------------------------------------------------------------
__global__ __launch_bounds__(256) void node_hidden_kernel(
    const float* __restrict__ msg, const float* __restrict__ v,
    float* __restrict__ nh) {
  __shared__ float Ms[32][129];
  __shared__ float Vs[128][33];
  const int blk = blockIdx.x;
  const int mblk = blk & 3;
  const int bh = blk >> 2;
  const int h = bh & 7;
  const int b = bh >> 3;
  const int t = threadIdx.x;

  {
    const int n = t & 127, r0 = t >> 7;
#pragma unroll
    for (int p = 0; p < 16; ++p) {
      const int r = r0 + p * 2;
      Ms[r][n] = msg[((size_t)bh * 128 + mblk * 32 + r) * 128 + n];
    }
  }
  {
    const int dk = t & 31, n0 = t >> 5;
#pragma unroll
    for (int p = 0; p < 16; ++p) {
      const int n = n0 + p * 8;
      Vs[n][dk] = v[((size_t)b * 128 + n) * 256 + h * 32 + dk];
    }
  }
  __syncthreads();

  const int dk = t & 31;
  const int mg = t >> 5;
  float acc[4] = {0.f, 0.f, 0.f, 0.f};
  for (int n = 0; n < 128; ++n) {
    const float vv = Vs[n][dk];
#pragma unroll
    for (int r = 0; r < 4; ++r) acc[r] = fmaf(Ms[mg + 8 * r][n], vv, acc[r]);
  }
#pragma unroll
  for (int r = 0; r < 4; ++r) {
    const int m = mblk * 32 + mg + 8 * r;
    nh[((size_t)b * 128 + m) * 256 + h * 32 + dk] = acc[r];
  }
}

// ---------------------------------------------------------------------------
// Fused edge: out = bf16( (ke@Wk^T + bk) .* msg ) @ Weo^T + beo, never
// materializing k. Block = 64 edge rows x 256 cols, two chained MFMA phases
// through an LDS bf16 intermediate K1[64][264].
// Both phases use swapped mfma(Wfrag, kefrag) -> transposed D so each lane
// holds 4 CONSECUTIVE output columns: ds_write_b64 into K1, float4 stores out.
// ---------------------------------------------------------------------------
__global__ __launch_bounds__(256) void edge_fused_kernel(
    const float* __restrict__ ke, const float* __restrict__ msg,
    const unsigned short* __restrict__ wk, const unsigned short* __restrict__ weo,
    const float* __restrict__ bk, const float* __restrict__ beo,
    float* __restrict__ out) {
  __shared__ __align__(16) unsigned short As[64 * 40];     //  5120 B
  __shared__ __align__(16) unsigned short Ws[256 * 40];    // 20480 B (Wk then Weo)
  __shared__ __align__(16) unsigned short K1[64 * 264];    // 33792 B intermediate
  __shared__ float Msgs[64][8];
  const int nblk = blockIdx.x;          // 0..1
  const int bm = blockIdx.y;            // 0..1023
  const int b = bm >> 7;
  const int m = bm & 127;
  const int n0 = nblk * 64;
  const int t = threadIdx.x;
  const int l = t & 63;
  const int w = t >> 6;                 // wave -> col group of 64
  const int lr = l & 15;
  const int lk = l >> 4;
  const size_t rowbase = ((size_t)bm * 128 + n0) * 256;

  // stage msg for these 64 rows x 8 heads
#pragma unroll
  for (int p = 0; p < 2; ++p) {
    const int idx = t + p * 256;
    const int r = idx >> 3, h = idx & 7;
    Msgs[r][h] = msg[(((size_t)(b * 8 + h) * 128 + m) * 128) + n0 + r];
  }

  floatx4 acc[4][4] = {};

  // -------- phase A: K1 = bf16( (ke @ Wk^T + bk) .* msg ) ----------------
  for (int kk = 0; kk < 256; kk += 32) {
    float4 av[2]; int arow[2], akc[2];
#pragma unroll
    for (int p = 0; p < 2; ++p) {
      const int f = p * 256 + t;
      arow[p] = f >> 3; akc[p] = (f & 7) * 4;
      av[p] = *(const float4*)&ke[rowbase + (size_t)arow[p] * 256 + kk + akc[p]];
    }
    uint4 wv[4];
#pragma unroll
    for (int p = 0; p < 4; ++p) {
      const int f = p * 256 + t;
      const int row = f >> 2, kc = (f & 3) * 8;
      wv[p] = *(const uint4*)&wk[(size_t)row * 256 + kk + kc];
    }
    __syncthreads();  // previous iteration's frag reads done (iter0: Msgs done)
#pragma unroll
    for (int p = 0; p < 2; ++p)
      *(ushort4*)&As[arow[p] * 40 + akc[p]] =
          make_ushort4(f2bf(av[p].x), f2bf(av[p].y), f2bf(av[p].z), f2bf(av[p].w));
#pragma unroll
    for (int p = 0; p < 4; ++p) {
      const int f = p * 256 + t;
      const int row = f >> 2, kc = (f & 3) * 8;
      *(uint4*)&Ws[row * 40 + kc] = wv[p];
    }
    __syncthreads();
    short8 a[4], bw[4];
#pragma unroll
    for (int i = 0; i < 4; ++i)
      a[i] = *(const short8*)&As[(i * 16 + lr) * 40 + lk * 8];
#pragma unroll
    for (int j = 0; j < 4; ++j)
      bw[j] = *(const short8*)&Ws[(w * 64 + j * 16 + lr) * 40 + lk * 8];
#pragma unroll
    for (int i = 0; i < 4; ++i)
#pragma unroll
      for (int j = 0; j < 4; ++j)   // swapped operands -> lane holds 4 consecutive cols
        acc[i][j] = __builtin_amdgcn_mfma_f32_16x16x32_bf16(bw[j], a[i], acc[i][j], 0, 0, 0);
  }

  // bias + per-head msg scale, pack bf16, ds_write_b64 to K1
#pragma unroll
  for (int j = 0; j < 4; ++j) {
    const int col = w * 64 + j * 16 + lk * 4;          // k-output dim o
    const float4 kb = *(const float4*)&bk[col];
    const int h = col >> 5;
#pragma unroll
    for (int i = 0; i < 4; ++i) {
      const int row = i * 16 + lr;                     // n-offset within tile
      const float sc = Msgs[row][h];
      *(ushort4*)&K1[row * 264 + col] = make_ushort4(
          f2bf((acc[i][j][0] + kb.x) * sc), f2bf((acc[i][j][1] + kb.y) * sc),
          f2bf((acc[i][j][2] + kb.z) * sc), f2bf((acc[i][j][3] + kb.w) * sc));
      acc[i][j] = (floatx4){0.f, 0.f, 0.f, 0.f};       // reuse for phase B
    }
  }
  __syncthreads();  // K1 complete; all phase-A Ws reads done

  // -------- phase B: out = K1 @ Weo^T + beo ------------------------------
  for (int kk = 0; kk < 256; kk += 32) {
    uint4 wv[4];
#pragma unroll
    for (int p = 0; p < 4; ++p) {
      const int f = p * 256 + t;
      const int row = f >> 2, kc = (f & 3) * 8;
      wv[p] = *(const uint4*)&weo[(size_t)row * 256 + kk + kc];
    }
    __syncthreads();  // previous iteration's frag reads done
#pragma unroll
    for (int p = 0; p < 4; ++p) {
      const int f = p * 256 + t;
      const int row = f >> 2, kc = (f & 3) * 8;
      *(uint4*)&Ws[row * 40 + kc] = wv[p];
    }
    __syncthreads();
    short8 ak[4], bw[4];
#pragma unroll
    for (int i = 0; i < 4; ++i)
      ak[i] = *(const short8*)&K1[(i * 16 + lr) * 264 + kk + lk * 8];
#pragma unroll
    for (int j = 0; j < 4; ++j)
      bw[j] = *(const short8*)&Ws[(w * 64 + j * 16 + lr) * 40 + lk * 8];
#pragma unroll
    for (int i = 0; i < 4; ++i)
#pragma unroll
      for (int j = 0; j < 4; ++j)
        acc[i][j] = __builtin_amdgcn_mfma_f32_16x16x32_bf16(bw[j], ak[i], acc[i][j], 0, 0, 0);
  }

  // epilogue: lane holds OUT[row=i*16+lr][col=w*64+j*16+lk*4 .. +3] -> float4
  float4 bj[4];
#pragma unroll
  for (int j = 0; j < 4; ++j) bj[j] = *(const float4*)&beo[w * 64 + j * 16 + lk * 4];
#pragma unroll
  for (int i = 0; i < 4; ++i) {
    const size_t rb = rowbase + (size_t)(i * 16 + lr) * 256;
#pragma unroll
    for (int j = 0; j < 4; ++j) {
      float4 o;
      o.x = acc[i][j][0] + bj[j].x;
      o.y = acc[i][j][1] + bj[j].y;
      o.z = acc[i][j][2] + bj[j].z;
      o.w = acc[i][j][3] + bj[j].w;
      *(float4*)&out[rb + w * 64 + j * 16 + lk * 4] = o;
    }
  }
}

// ---------------------------------------------------------------------------
extern "C" void kernel_launch(void* const* d_in, const int* in_sizes, int n_in,
                              void* d_out, int out_size, void* d_ws, size_t ws_size,
                              hipStream_t stream) {
  (void)in_sizes; (void)n_in; (void)out_size; (void)ws_size;
  const float* query_node = (const float*)d_in[0];
  const float* value_node = (const float*)d_in[1];
  const float* key_edge   = (const float*)d_in[2];
  const float* adj_matrix = (const float*)d_in[3];
  const int*   mask       = (const int*)d_in[4];
  const float* Wq  = (const float*)d_in[5];
  const float* bq  = (const float*)d_in[6];
  const float* Wk  = (const float*)d_in[7];
  const float* bk  = (const float*)d_in[8];
  const float* Wv  = (const float*)d_in[9];
  const float* bv  = (const float*)d_in[10];
  const float* Wno = (const float*)d_in[11];
  const float* bno = (const float*)d_in[12];
  const float* Weo = (const float*)d_in[13];
  const float* beo = (const float*)d_in[14];
  const float* lam = (const float*)d_in[15];

  float* out = (float*)d_out;
  float* node_out = out;                                  // [B,N,D]
  float* edge_out = out + (size_t)Bc * Nc * Dc;           // [B,N,N,D]

  float* ws = (float*)d_ws;
  float* q    = ws; ws += (size_t)Bc * Nc * Dc;
  float* v    = ws; ws += (size_t)Bc * Nc * Dc;
  float* adjs = ws; ws += (size_t)Bc * Nc * Nc;
  float* osc  = ws; ws += (size_t)Bc * Hc * Nc * Nc;
  float* isc  = ws; ws += (size_t)Bc * Hc * Nc * Nc;
  float* msg  = ws; ws += (size_t)Bc * Hc * Nc * Nc;
  float* nh   = ws; ws += (size_t)Bc * Nc * Dc;
  unsigned short* wkbf  = (unsigned short*)ws; ws += 32768;   // 65536 bf16
  unsigned short* weobf = (unsigned short*)ws; ws += 32768;   // 65536 bf16

  // pre-cast weights to bf16 (MFMA kernel inputs)
  cast_bf16_kernel<<<dim3(64), 256, 0, stream>>>(Wk, wkbf, Dc * Dc);
  cast_bf16_kernel<<<dim3(64), 256, 0, stream>>>(Weo, weobf, Dc * Dc);
  // q, v projections (fp32, small)
  gemm_xwT_kernel<<<dim3(4, 16), 256, 0, stream>>>(query_node, Wq, bq, q, Bc * Nc);
  gemm_xwT_kernel<<<dim3(4, 16), 256, 0, stream>>>(value_node, Wv, bv, v, Bc * Nc);
  // adjacency softmax
  adj_softmax_kernel<<<dim3(Bc * Nc), 128, 0, stream>>>(adj_matrix, mask, lam, adjs);
  // k-tiles via MFMA + both score tensors, k never hits HBM
  kscore_kernel<<<dim3(2, 1024), 256, 0, stream>>>(key_edge, q, wkbf, bk, osc, isc);
  // softmaxes + message
  message_kernel<<<dim3(Bc * Hc * Nc), 128, 0, stream>>>(osc, isc, adjs, mask, msg);
  // node hidden + node projection (fp32)
  node_hidden_kernel<<<dim3(Bc * Hc * 4), 256, 0, stream>>>(msg, v, nh);
  gemm_xwT_kernel<<<dim3(4, 16), 256, 0, stream>>>(nh, Wno, bno, node_out, Bc * Nc);
  // fused edge pipeline: ke -> k -> msg-scale -> Weo projection (one pass)
  edge_fused_kernel<<<dim3(2, 1024), 256, 0, stream>>>(
      key_edge, msg, wkbf, weobf, bk, beo, edge_out);
}

// Round 4
// 543.208 us; speedup vs baseline: 1.2641x; 1.0669x over previous
//
#include <hip/hip_runtime.h>
#include <math.h>

#define Bc 8
#define Nc 128
#define Dc 256
#define Hc 8
#define DKc 32

typedef __attribute__((ext_vector_type(8))) short short8;
typedef __attribute__((ext_vector_type(4))) float floatx4;

__device__ __forceinline__ unsigned short f2bf(float f) {
  unsigned int u = __float_as_uint(f);
  u += 0x7FFFu + ((u >> 16) & 1u);   // RNE to bf16 (inputs are normal floats)
  return (unsigned short)(u >> 16);
}

__device__ __forceinline__ float bf2f(unsigned short s) {
  return __uint_as_float(((unsigned int)s) << 16);
}

// ---------------------------------------------------------------------------
// cast fp32 -> bf16 (for Wk, Weo; 65536 elements each)
// ---------------------------------------------------------------------------
__global__ __launch_bounds__(256) void cast_bf16_kernel(
    const float* __restrict__ src, unsigned short* __restrict__ dst, int n) {
  const int i = (blockIdx.x * 256 + threadIdx.x) * 4;
  if (i < n) {
    const float4 v = *(const float4*)&src[i];
    *(ushort4*)&dst[i] = make_ushort4(f2bf(v.x), f2bf(v.y), f2bf(v.z), f2bf(v.w));
  }
}

// ---------------------------------------------------------------------------
// Small GEMM (fp32): C[M,256] = X @ W^T + b. 64x64 tile. q/v/node projections.
// ---------------------------------------------------------------------------
__global__ __launch_bounds__(256) void gemm_xwT_kernel(
    const float* __restrict__ X, const float* __restrict__ W,
    const float* __restrict__ bias, float* __restrict__ C, int M) {
  __shared__ float As[64][17];
  __shared__ float Ws[64][17];
  const int t = threadIdx.x;
  const int tx = t & 15;
  const int ty = t >> 4;
  const size_t row0 = (size_t)blockIdx.y * 64;
  const int col0 = blockIdx.x * 64;
  const int lr = t >> 2;
  const int lc = (t & 3) * 4;

  float acc[4][4] = {};

  for (int kk = 0; kk < 256; kk += 16) {
    float4 av = *(const float4*)&X[(row0 + lr) * 256 + kk + lc];
    float4 wv = *(const float4*)&W[(size_t)(col0 + lr) * 256 + kk + lc];
    As[lr][lc] = av.x; As[lr][lc + 1] = av.y; As[lr][lc + 2] = av.z; As[lr][lc + 3] = av.w;
    Ws[lr][lc] = wv.x; Ws[lr][lc + 1] = wv.y; Ws[lr][lc + 2] = wv.z; Ws[lr][lc + 3] = wv.w;
    __syncthreads();
#pragma unroll
    for (int e = 0; e < 16; ++e) {
      float a[4], w[4];
#pragma unroll
      for (int r = 0; r < 4; ++r) a[r] = As[ty * 4 + r][e];
#pragma unroll
      for (int c = 0; c < 4; ++c) w[c] = Ws[tx * 4 + c][e];
#pragma unroll
      for (int r = 0; r < 4; ++r)
#pragma unroll
        for (int c = 0; c < 4; ++c) acc[r][c] = fmaf(a[r], w[c], acc[r][c]);
    }
    __syncthreads();
  }

  const float4 bv = *(const float4*)&bias[col0 + tx * 4];
#pragma unroll
  for (int r = 0; r < 4; ++r) {
    float4 o;
    o.x = acc[r][0] + bv.x;
    o.y = acc[r][1] + bv.y;
    o.z = acc[r][2] + bv.z;
    o.w = acc[r][3] + bv.w;
    *(float4*)&C[(row0 + ty * 4 + r) * 256 + col0 + tx * 4] = o;
  }
}

// ---------------------------------------------------------------------------
// adjacency softmax (unchanged)
// ---------------------------------------------------------------------------
__global__ __launch_bounds__(128) void adj_softmax_kernel(
    const float* __restrict__ adj, const int* __restrict__ mask,
    const float* __restrict__ lam_p, float* __restrict__ adjs) {
  __shared__ float red[128];
  const int bi = blockIdx.x;
  const int b = bi >> 7;
  const int j = threadIdx.x;
  const float lam = lam_p[0];
  float x = (mask[b * 128 + j] != 0) ? (-lam * adj[(size_t)bi * 128 + j]) : -INFINITY;
  red[j] = x; __syncthreads();
  for (int s = 64; s > 0; s >>= 1) { if (j < s) red[j] = fmaxf(red[j], red[j + s]); __syncthreads(); }
  const float mx = red[0]; __syncthreads();
  const float e = expf(x - mx);
  red[j] = e; __syncthreads();
  for (int s = 64; s > 0; s >>= 1) { if (j < s) red[j] += red[j + s]; __syncthreads(); }
  const float z = red[0];
  adjs[(size_t)bi * 128 + j] = e / z;
}

// ---------------------------------------------------------------------------
// kscore: compute k-tile (64 edge rows x 256 k-dims) via bf16 MFMA from
// key_edge, then (a) BOTH score tensors straight from the accumulators and
// (b) stash bf16(k) into the UPPER 512 B of each edge-out row's 1 KiB slot
// (edge[g*1024 + 512 ..)), to be consumed (and then overwritten) by edge2.
//   osc[b,h,m,n] = inv_sqrt * sum_d q[b,m,h*32+d] * K[n, h*32+d]
//   isc[b,h,n,m] = inv_sqrt * sum_d q[b,n,h*32+d] * K[n, h*32+d]
// Swapped mfma(Wfrag, kefrag): lane holds rows i*16+lr, cols
// w*64+j*16+lk*4+r (4 consecutive k-dims). Wave's cols span heads {2w,2w+1};
// per-(row,head) sums finish with shfl_xor over the 4 lk-lanes.
// ---------------------------------------------------------------------------
__global__ __launch_bounds__(256) void kscore_kernel(
    const float* __restrict__ ke, const float* __restrict__ q,
    const unsigned short* __restrict__ wk, const float* __restrict__ bk,
    float* __restrict__ osc, float* __restrict__ isc,
    float* __restrict__ edge /* bf16-k stash region */) {
  __shared__ __align__(16) unsigned short As[64 * 40];     //  5120 B
  __shared__ __align__(16) unsigned short Ws[256 * 40];    // 20480 B
  const int nblk = blockIdx.x;          // 0..1
  const int bm = blockIdx.y;            // 0..1023
  const int b = bm >> 7;
  const int m = bm & 127;
  const int n0 = nblk * 64;
  const int t = threadIdx.x;
  const int l = t & 63;
  const int w = t >> 6;                 // wave -> k-col group of 64 (heads 2w,2w+1)
  const int lr = l & 15;
  const int lk = l >> 4;
  const size_t rowbase = ((size_t)bm * 128 + n0) * 256;
  unsigned short* kbf = (unsigned short*)edge;

  floatx4 acc[4][4] = {};

  for (int kk = 0; kk < 256; kk += 32) {
    float4 av[2]; int arow[2], akc[2];
#pragma unroll
    for (int p = 0; p < 2; ++p) {
      const int f = p * 256 + t;
      arow[p] = f >> 3; akc[p] = (f & 7) * 4;
      av[p] = *(const float4*)&ke[rowbase + (size_t)arow[p] * 256 + kk + akc[p]];
    }
    uint4 wv[4];
#pragma unroll
    for (int p = 0; p < 4; ++p) {
      const int f = p * 256 + t;
      const int row = f >> 2, kc = (f & 3) * 8;
      wv[p] = *(const uint4*)&wk[(size_t)row * 256 + kk + kc];
    }
    __syncthreads();  // previous iteration's frag reads done
#pragma unroll
    for (int p = 0; p < 2; ++p)
      *(ushort4*)&As[arow[p] * 40 + akc[p]] =
          make_ushort4(f2bf(av[p].x), f2bf(av[p].y), f2bf(av[p].z), f2bf(av[p].w));
#pragma unroll
    for (int p = 0; p < 4; ++p) {
      const int f = p * 256 + t;
      const int row = f >> 2, kc = (f & 3) * 8;
      *(uint4*)&Ws[row * 40 + kc] = wv[p];
    }
    __syncthreads();
    short8 a[4], bw[4];
#pragma unroll
    for (int i = 0; i < 4; ++i)
      a[i] = *(const short8*)&As[(i * 16 + lr) * 40 + lk * 8];
#pragma unroll
    for (int j = 0; j < 4; ++j)
      bw[j] = *(const short8*)&Ws[(w * 64 + j * 16 + lr) * 40 + lk * 8];
#pragma unroll
    for (int i = 0; i < 4; ++i)
#pragma unroll
      for (int j = 0; j < 4; ++j)   // swapped -> lane holds 4 consecutive k-cols
        acc[i][j] = __builtin_amdgcn_mfma_f32_16x16x32_bf16(bw[j], a[i], acc[i][j], 0, 0, 0);
  }

  const float inv_sqrt = 0.17677669529663687f;
  float4 qm4[4], kb4[4];
#pragma unroll
  for (int j = 0; j < 4; ++j) {
    qm4[j] = *(const float4*)&q[((size_t)(b * 128 + m)) * 256 + w * 64 + j * 16 + lk * 4];
    kb4[j] = *(const float4*)&bk[w * 64 + j * 16 + lk * 4];
  }
#pragma unroll
  for (int i = 0; i < 4; ++i) {
    const int ng = n0 + i * 16 + lr;
    const size_t gkb = (size_t)bm * 128 + ng;       // global edge row
    const size_t qnb = ((size_t)(b * 128 + ng)) * 256 + w * 64 + lk * 4;
    float po0 = 0.f, po1 = 0.f, pi0 = 0.f, pi1 = 0.f;
#pragma unroll
    for (int j = 0; j < 4; ++j) {
      const float4 qn = *(const float4*)&q[qnb + j * 16];
      const float k0 = acc[i][j][0] + kb4[j].x;
      const float k1 = acc[i][j][1] + kb4[j].y;
      const float k2 = acc[i][j][2] + kb4[j].z;
      const float k3 = acc[i][j][3] + kb4[j].w;
      // stash bf16(k) in the upper half of this row's out slot
      *(ushort4*)&kbf[gkb * 512 + 256 + w * 64 + j * 16 + lk * 4] =
          make_ushort4(f2bf(k0), f2bf(k1), f2bf(k2), f2bf(k3));
      const float so = fmaf(k0, qm4[j].x, fmaf(k1, qm4[j].y, fmaf(k2, qm4[j].z, k3 * qm4[j].w)));
      const float si = fmaf(k0, qn.x, fmaf(k1, qn.y, fmaf(k2, qn.z, k3 * qn.w)));
      if (j < 2) { po0 += so; pi0 += si; } else { po1 += so; pi1 += si; }
    }
    po0 += __shfl_xor(po0, 16, 64); po0 += __shfl_xor(po0, 32, 64);
    po1 += __shfl_xor(po1, 16, 64); po1 += __shfl_xor(po1, 32, 64);
    pi0 += __shfl_xor(pi0, 16, 64); pi0 += __shfl_xor(pi0, 32, 64);
    pi1 += __shfl_xor(pi1, 16, 64); pi1 += __shfl_xor(pi1, 32, 64);
    if (lk == 0) {
      const int h0 = w * 2, h1 = w * 2 + 1;
      osc[((size_t)(b * 8 + h0) * 128 + m) * 128 + ng] = po0 * inv_sqrt;
      osc[((size_t)(b * 8 + h1) * 128 + m) * 128 + ng] = po1 * inv_sqrt;
      isc[((size_t)(b * 8 + h0) * 128 + ng) * 128 + m] = pi0 * inv_sqrt;
      isc[((size_t)(b * 8 + h1) * 128 + ng) * 128 + m] = pi1 * inv_sqrt;
    }
  }
}

// ---------------------------------------------------------------------------
// message (unchanged)
// ---------------------------------------------------------------------------
__global__ __launch_bounds__(128) void message_kernel(
    const float* __restrict__ osc, const float* __restrict__ isc,
    const float* __restrict__ adjs, const int* __restrict__ mask,
    float* __restrict__ msg) {
  __shared__ float red[128];
  const int bhi = blockIdx.x;
  const int i = bhi & 127;
  const int b = bhi >> 10;
  const int j = threadIdx.x;
  const bool mj = mask[b * 128 + j] != 0;

  const float so = mj ? osc[(size_t)bhi * 128 + j] : -INFINITY;
  const float si = mj ? isc[(size_t)bhi * 128 + j] : -INFINITY;

  red[j] = so; __syncthreads();
  for (int s = 64; s > 0; s >>= 1) { if (j < s) red[j] = fmaxf(red[j], red[j + s]); __syncthreads(); }
  const float mo = red[0]; __syncthreads();
  const float eo = expf(so - mo);
  red[j] = eo; __syncthreads();
  for (int s = 64; s > 0; s >>= 1) { if (j < s) red[j] += red[j + s]; __syncthreads(); }
  const float zo = red[0]; __syncthreads();
  const float oa = eo / zo;

  red[j] = si; __syncthreads();
  for (int s = 64; s > 0; s >>= 1) { if (j < s) red[j] = fmaxf(red[j], red[j + s]); __syncthreads(); }
  const float mi = red[0]; __syncthreads();
  const float ei = expf(si - mi);
  red[j] = ei; __syncthreads();
  for (int s = 64; s > 0; s >>= 1) { if (j < s) red[j] += red[j + s]; __syncthreads(); }
  const float zi = red[0];
  const float ia = ei / zi;

  float val = oa + ia - ((i == j) ? oa : 0.0f);
  val *= adjs[((size_t)(b * 128 + i)) * 128 + j];
  msg[(size_t)bhi * 128 + j] = val;
}

// ---------------------------------------------------------------------------
// node_hidden (unchanged)
// ---------------------------------------------------------------------------
__global__ __launch_bounds__(256) void node_hidden_kernel(
    const float* __restrict__ msg, const float* __restrict__ v,
    float* __restrict__ nh) {
  __shared__ float Ms[32][129];
  __shared__ float Vs[128][33];
  const int blk = blockIdx.x;
  const int mblk = blk & 3;
  const int bh = blk >> 2;
  const int h = bh & 7;
  const int b = bh >> 3;
  const int t = threadIdx.x;

  {
    const int n = t & 127, r0 = t >> 7;
#pragma unroll
    for (int p = 0; p < 16; ++p) {
      const int r = r0 + p * 2;
      Ms[r][n] = msg[((size_t)bh * 128 + mblk * 32 + r) * 128 + n];
    }
  }
  {
    const int dk = t & 31, n0 = t >> 5;
#pragma unroll
    for (int p = 0; p < 16; ++p) {
      const int n = n0 + p * 8;
      Vs[n][dk] = v[((size_t)b * 128 + n) * 256 + h * 32 + dk];
    }
  }
  __syncthreads();

  const int dk = t & 31;
  const int mg = t >> 5;
  float acc[4] = {0.f, 0.f, 0.f, 0.f};
  for (int n = 0; n < 128; ++n) {
    const float vv = Vs[n][dk];
#pragma unroll
    for (int r = 0; r < 4; ++r) acc[r] = fmaf(Ms[mg + 8 * r][n], vv, acc[r]);
  }
#pragma unroll
  for (int r = 0; r < 4; ++r) {
    const int m = mblk * 32 + mg + 8 * r;
    nh[((size_t)b * 128 + m) * 256 + h * 32 + dk] = acc[r];
  }
}

// ---------------------------------------------------------------------------
// edge2: out = bf16( kbf .* msg ) @ Weo^T + beo, where kbf = bf16 k stashed
// by kscore in the upper 512 B of each out row's 1 KiB slot. Reads and final
// writes alias row-exactly: every kbf load completes before the last barrier
// (value consumed by the LDS write preceding it), epilogue stores come after.
// 27.6 KB LDS -> 5 blocks/CU headroom. Swapped MFMA -> float4 out stores.
// ---------------------------------------------------------------------------
__global__ __launch_bounds__(256) void edge2_kernel(
    float* edge, const float* __restrict__ msg,
    const unsigned short* __restrict__ weo, const float* __restrict__ beo) {
  __shared__ __align__(16) unsigned short As[64 * 40];     //  5120 B
  __shared__ __align__(16) unsigned short Ws[256 * 40];    // 20480 B
  __shared__ float Msgs[64][8];
  const int nblk = blockIdx.x;          // 0..1
  const int bm = blockIdx.y;            // 0..1023
  const int b = bm >> 7;
  const int m = bm & 127;
  const int n0 = nblk * 64;
  const int t = threadIdx.x;
  const int l = t & 63;
  const int w = t >> 6;                 // wave -> out col group of 64
  const int lr = l & 15;
  const int lk = l >> 4;
  const unsigned short* kbf = (const unsigned short*)edge;
  const size_t g0 = (size_t)bm * 128 + n0;   // first global edge row

  // stage msg for these 64 rows x 8 heads
#pragma unroll
  for (int p = 0; p < 2; ++p) {
    const int idx = t + p * 256;
    const int r = idx >> 3, h = idx & 7;
    Msgs[r][h] = msg[(((size_t)(b * 8 + h) * 128 + m) * 128) + n0 + r];
  }

  floatx4 acc[4][4] = {};
  const int arow = t >> 2, akc = (t & 3) * 8;

  for (int kk = 0; kk < 256; kk += 32) {
    const int h = kk >> 5;                  // head of this K-chunk
    const uint4 kv = *(const uint4*)&kbf[(g0 + arow) * 512 + 256 + kk + akc];
    uint4 wv[4];
#pragma unroll
    for (int p = 0; p < 4; ++p) {
      const int f = p * 256 + t;
      const int row = f >> 2, kc = (f & 3) * 8;
      wv[p] = *(const uint4*)&weo[(size_t)row * 256 + kk + kc];
    }
    __syncthreads();  // previous iteration's frag reads done (iter0: Msgs done)
    {
      const float sc = Msgs[arow][h];
      const unsigned short* us = (const unsigned short*)&kv;
      unsigned short o[8];
#pragma unroll
      for (int e = 0; e < 8; ++e) o[e] = f2bf(bf2f(us[e]) * sc);
      *(ushort4*)&As[arow * 40 + akc]     = make_ushort4(o[0], o[1], o[2], o[3]);
      *(ushort4*)&As[arow * 40 + akc + 4] = make_ushort4(o[4], o[5], o[6], o[7]);
    }
#pragma unroll
    for (int p = 0; p < 4; ++p) {
      const int f = p * 256 + t;
      const int row = f >> 2, kc = (f & 3) * 8;
      *(uint4*)&Ws[row * 40 + kc] = wv[p];
    }
    __syncthreads();
    short8 a[4], bw[4];
#pragma unroll
    for (int i = 0; i < 4; ++i)
      a[i] = *(const short8*)&As[(i * 16 + lr) * 40 + lk * 8];
#pragma unroll
    for (int j = 0; j < 4; ++j)
      bw[j] = *(const short8*)&Ws[(w * 64 + j * 16 + lr) * 40 + lk * 8];
#pragma unroll
    for (int i = 0; i < 4; ++i)
#pragma unroll
      for (int j = 0; j < 4; ++j)   // swapped operands -> lane holds 4 consecutive cols
        acc[i][j] = __builtin_amdgcn_mfma_f32_16x16x32_bf16(bw[j], a[i], acc[i][j], 0, 0, 0);
  }

  // epilogue: lane holds OUT[row=i*16+lr][col=w*64+j*16+lk*4 .. +3] -> float4
  float4 bj[4];
#pragma unroll
  for (int j = 0; j < 4; ++j) bj[j] = *(const float4*)&beo[w * 64 + j * 16 + lk * 4];
  const size_t rowbase = g0 * 256;
#pragma unroll
  for (int i = 0; i < 4; ++i) {
    const size_t rb = rowbase + (size_t)(i * 16 + lr) * 256;
#pragma unroll
    for (int j = 0; j < 4; ++j) {
      float4 o;
      o.x = acc[i][j][0] + bj[j].x;
      o.y = acc[i][j][1] + bj[j].y;
      o.z = acc[i][j][2] + bj[j].z;
      o.w = acc[i][j][3] + bj[j].w;
      *(float4*)&edge[rb + w * 64 + j * 16 + lk * 4] = o;
    }
  }
}

// ---------------------------------------------------------------------------
extern "C" void kernel_launch(void* const* d_in, const int* in_sizes, int n_in,
                              void* d_out, int out_size, void* d_ws, size_t ws_size,
                              hipStream_t stream) {
  (void)in_sizes; (void)n_in; (void)out_size; (void)ws_size;
  const float* query_node = (const float*)d_in[0];
  const float* value_node = (const float*)d_in[1];
  const float* key_edge   = (const float*)d_in[2];
  const float* adj_matrix = (const float*)d_in[3];
  const int*   mask       = (const int*)d_in[4];
  const float* Wq  = (const float*)d_in[5];
  const float* bq  = (const float*)d_in[6];
  const float* Wk  = (const float*)d_in[7];
  const float* bk  = (const float*)d_in[8];
  const float* Wv  = (const float*)d_in[9];
  const float* bv  = (const float*)d_in[10];
  const float* Wno = (const float*)d_in[11];
  const float* bno = (const float*)d_in[12];
  const float* Weo = (const float*)d_in[13];
  const float* beo = (const float*)d_in[14];
  const float* lam = (const float*)d_in[15];

  float* out = (float*)d_out;
  float* node_out = out;                                  // [B,N,D]
  float* edge_out = out + (size_t)Bc * Nc * Dc;           // [B,N,N,D]; upper half
                                                          // of each row = bf16-k stash

  float* ws = (float*)d_ws;
  float* q    = ws; ws += (size_t)Bc * Nc * Dc;
  float* v    = ws; ws += (size_t)Bc * Nc * Dc;
  float* adjs = ws; ws += (size_t)Bc * Nc * Nc;
  float* osc  = ws; ws += (size_t)Bc * Hc * Nc * Nc;
  float* isc  = ws; ws += (size_t)Bc * Hc * Nc * Nc;
  float* msg  = ws; ws += (size_t)Bc * Hc * Nc * Nc;
  float* nh   = ws; ws += (size_t)Bc * Nc * Dc;
  unsigned short* wkbf  = (unsigned short*)ws; ws += 32768;   // 65536 bf16
  unsigned short* weobf = (unsigned short*)ws; ws += 32768;   // 65536 bf16

  // pre-cast weights to bf16 (MFMA kernel inputs)
  cast_bf16_kernel<<<dim3(64), 256, 0, stream>>>(Wk, wkbf, Dc * Dc);
  cast_bf16_kernel<<<dim3(64), 256, 0, stream>>>(Weo, weobf, Dc * Dc);
  // q, v projections (fp32, small)
  gemm_xwT_kernel<<<dim3(4, 16), 256, 0, stream>>>(query_node, Wq, bq, q, Bc * Nc);
  gemm_xwT_kernel<<<dim3(4, 16), 256, 0, stream>>>(value_node, Wv, bv, v, Bc * Nc);
  // adjacency softmax
  adj_softmax_kernel<<<dim3(Bc * Nc), 128, 0, stream>>>(adj_matrix, mask, lam, adjs);
  // k via MFMA -> both score tensors + bf16-k stash in edge_out upper halves
  kscore_kernel<<<dim3(2, 1024), 256, 0, stream>>>(key_edge, q, wkbf, bk, osc, isc, edge_out);
  // softmaxes + message
  message_kernel<<<dim3(Bc * Hc * Nc), 128, 0, stream>>>(osc, isc, adjs, mask, msg);
  // node hidden + node projection (fp32)
  node_hidden_kernel<<<dim3(Bc * Hc * 4), 256, 0, stream>>>(msg, v, nh);
  gemm_xwT_kernel<<<dim3(4, 16), 256, 0, stream>>>(nh, Wno, bno, node_out, Bc * Nc);
  // edge output: msg-scale stashed bf16 k, project with Weo (in-place safe)
  edge2_kernel<<<dim3(2, 1024), 256, 0, stream>>>(edge_out, msg, weobf, beo);
}

// Round 5
// 489.520 us; speedup vs baseline: 1.4028x; 1.1097x over previous
//
#include <hip/hip_runtime.h>
#include <math.h>

#define Bc 8
#define Nc 128
#define Dc 256
#define Hc 8
#define DKc 32

typedef __attribute__((ext_vector_type(8))) short short8;
typedef __attribute__((ext_vector_type(4))) float floatx4;

__device__ __forceinline__ unsigned short f2bf(float f) {
  unsigned int u = __float_as_uint(f);
  u += 0x7FFFu + ((u >> 16) & 1u);   // RNE to bf16 (inputs are normal floats)
  return (unsigned short)(u >> 16);
}

__device__ __forceinline__ float bf2f(unsigned short s) {
  return __uint_as_float(((unsigned int)s) << 16);
}

__device__ __forceinline__ short8 f2bf8(float4 lo, float4 hi) {
  short8 r;
  r[0] = (short)f2bf(lo.x); r[1] = (short)f2bf(lo.y);
  r[2] = (short)f2bf(lo.z); r[3] = (short)f2bf(lo.w);
  r[4] = (short)f2bf(hi.x); r[5] = (short)f2bf(hi.y);
  r[6] = (short)f2bf(hi.z); r[7] = (short)f2bf(hi.w);
  return r;
}

// ---------------------------------------------------------------------------
// cast fp32 -> bf16 (for Wk, Weo; 65536 elements each)
// ---------------------------------------------------------------------------
__global__ __launch_bounds__(256) void cast_bf16_kernel(
    const float* __restrict__ src, unsigned short* __restrict__ dst, int n) {
  const int i = (blockIdx.x * 256 + threadIdx.x) * 4;
  if (i < n) {
    const float4 v = *(const float4*)&src[i];
    *(ushort4*)&dst[i] = make_ushort4(f2bf(v.x), f2bf(v.y), f2bf(v.z), f2bf(v.w));
  }
}

// ---------------------------------------------------------------------------
// Small GEMM (fp32): C[M,256] = X @ W^T + b. 64x64 tile. q/v/node projections.
// ---------------------------------------------------------------------------
__global__ __launch_bounds__(256) void gemm_xwT_kernel(
    const float* __restrict__ X, const float* __restrict__ W,
    const float* __restrict__ bias, float* __restrict__ C, int M) {
  __shared__ float As[64][17];
  __shared__ float Ws[64][17];
  const int t = threadIdx.x;
  const int tx = t & 15;
  const int ty = t >> 4;
  const size_t row0 = (size_t)blockIdx.y * 64;
  const int col0 = blockIdx.x * 64;
  const int lr = t >> 2;
  const int lc = (t & 3) * 4;

  float acc[4][4] = {};

  for (int kk = 0; kk < 256; kk += 16) {
    float4 av = *(const float4*)&X[(row0 + lr) * 256 + kk + lc];
    float4 wv = *(const float4*)&W[(size_t)(col0 + lr) * 256 + kk + lc];
    As[lr][lc] = av.x; As[lr][lc + 1] = av.y; As[lr][lc + 2] = av.z; As[lr][lc + 3] = av.w;
    Ws[lr][lc] = wv.x; Ws[lr][lc + 1] = wv.y; Ws[lr][lc + 2] = wv.z; Ws[lr][lc + 3] = wv.w;
    __syncthreads();
#pragma unroll
    for (int e = 0; e < 16; ++e) {
      float a[4], w[4];
#pragma unroll
      for (int r = 0; r < 4; ++r) a[r] = As[ty * 4 + r][e];
#pragma unroll
      for (int c = 0; c < 4; ++c) w[c] = Ws[tx * 4 + c][e];
#pragma unroll
      for (int r = 0; r < 4; ++r)
#pragma unroll
        for (int c = 0; c < 4; ++c) acc[r][c] = fmaf(a[r], w[c], acc[r][c]);
    }
    __syncthreads();
  }

  const float4 bv = *(const float4*)&bias[col0 + tx * 4];
#pragma unroll
  for (int r = 0; r < 4; ++r) {
    float4 o;
    o.x = acc[r][0] + bv.x;
    o.y = acc[r][1] + bv.y;
    o.z = acc[r][2] + bv.z;
    o.w = acc[r][3] + bv.w;
    *(float4*)&C[(row0 + ty * 4 + r) * 256 + col0 + tx * 4] = o;
  }
}

// ---------------------------------------------------------------------------
// adjacency softmax (unchanged)
// ---------------------------------------------------------------------------
__global__ __launch_bounds__(128) void adj_softmax_kernel(
    const float* __restrict__ adj, const int* __restrict__ mask,
    const float* __restrict__ lam_p, float* __restrict__ adjs) {
  __shared__ float red[128];
  const int bi = blockIdx.x;
  const int b = bi >> 7;
  const int j = threadIdx.x;
  const float lam = lam_p[0];
  float x = (mask[b * 128 + j] != 0) ? (-lam * adj[(size_t)bi * 128 + j]) : -INFINITY;
  red[j] = x; __syncthreads();
  for (int s = 64; s > 0; s >>= 1) { if (j < s) red[j] = fmaxf(red[j], red[j + s]); __syncthreads(); }
  const float mx = red[0]; __syncthreads();
  const float e = expf(x - mx);
  red[j] = e; __syncthreads();
  for (int s = 64; s > 0; s >>= 1) { if (j < s) red[j] += red[j + s]; __syncthreads(); }
  const float z = red[0];
  adjs[(size_t)bi * 128 + j] = e / z;
}

// ---------------------------------------------------------------------------
// kscore v2 — barrier-free, LDS-free. Each lane loads its MFMA fragments
// directly from global (ke fp32 -> bf16 in-register; wk already bf16).
// A-tile (64 rows) is block-shared data served by L2; wk is L2-resident.
// Outputs:
//   osc [b,h,m,n] = inv_sqrt * (q[b,m,h*32:].K[n,h*32:])      (contiguous n)
//   iscT[b,h,m,n] = inv_sqrt * (q[b,n,h*32:].K[n,h*32:])      (contiguous n;
//        = in_scores[b,h,n,m] transposed to kill write scatter)
//   stash bf16(K) into upper 512 B of each edge-out row's 1 KiB slot.
// Swapped mfma(Wfrag, kefrag): lane holds rows i*16+lr, cols
// w*64+j*16+lk*4+r. Wave's cols span heads {2w,2w+1}; per-(row,head) sums
// finish with shfl_xor over the 4 lk-lanes.
// ---------------------------------------------------------------------------
__global__ __launch_bounds__(256) void kscore_kernel(
    const float* __restrict__ ke, const float* __restrict__ q,
    const unsigned short* __restrict__ wk, const float* __restrict__ bk,
    float* __restrict__ osc, float* __restrict__ iscT,
    float* __restrict__ edge /* bf16-k stash region */) {
  const int nblk = blockIdx.x;          // 0..1
  const int bm = blockIdx.y;            // 0..1023
  const int b = bm >> 7;
  const int m = bm & 127;
  const int n0 = nblk * 64;
  const int t = threadIdx.x;
  const int l = t & 63;
  const int w = t >> 6;                 // wave -> k-col group of 64 (heads 2w,2w+1)
  const int lr = l & 15;
  const int lk = l >> 4;
  const size_t rowbase = ((size_t)bm * 128 + n0) * 256;
  unsigned short* kbf = (unsigned short*)edge;

  floatx4 acc[4][4] = {};

#pragma unroll 2
  for (int c = 0; c < 8; ++c) {
    const int kk = c * 32;
    short8 a[4], bw[4];
#pragma unroll
    for (int i = 0; i < 4; ++i) {
      const size_t base = rowbase + (size_t)(i * 16 + lr) * 256 + kk + lk * 8;
      const float4 f0 = *(const float4*)&ke[base];
      const float4 f1 = *(const float4*)&ke[base + 4];
      a[i] = f2bf8(f0, f1);
    }
#pragma unroll
    for (int j = 0; j < 4; ++j)
      bw[j] = *(const short8*)&wk[(size_t)(w * 64 + j * 16 + lr) * 256 + kk + lk * 8];
#pragma unroll
    for (int i = 0; i < 4; ++i)
#pragma unroll
      for (int j = 0; j < 4; ++j)   // swapped -> lane holds 4 consecutive k-cols
        acc[i][j] = __builtin_amdgcn_mfma_f32_16x16x32_bf16(bw[j], a[i], acc[i][j], 0, 0, 0);
  }

  const float inv_sqrt = 0.17677669529663687f;
  float4 qm4[4], kb4[4];
#pragma unroll
  for (int j = 0; j < 4; ++j) {
    qm4[j] = *(const float4*)&q[((size_t)(b * 128 + m)) * 256 + w * 64 + j * 16 + lk * 4];
    kb4[j] = *(const float4*)&bk[w * 64 + j * 16 + lk * 4];
  }
#pragma unroll
  for (int i = 0; i < 4; ++i) {
    const int ng = n0 + i * 16 + lr;
    const size_t gkb = (size_t)bm * 128 + ng;       // global edge row
    const size_t qnb = ((size_t)(b * 128 + ng)) * 256 + w * 64 + lk * 4;
    float po0 = 0.f, po1 = 0.f, pi0 = 0.f, pi1 = 0.f;
#pragma unroll
    for (int j = 0; j < 4; ++j) {
      const float4 qn = *(const float4*)&q[qnb + j * 16];
      const float k0 = acc[i][j][0] + kb4[j].x;
      const float k1 = acc[i][j][1] + kb4[j].y;
      const float k2 = acc[i][j][2] + kb4[j].z;
      const float k3 = acc[i][j][3] + kb4[j].w;
      // stash bf16(k) in the upper half of this row's out slot
      *(ushort4*)&kbf[gkb * 512 + 256 + w * 64 + j * 16 + lk * 4] =
          make_ushort4(f2bf(k0), f2bf(k1), f2bf(k2), f2bf(k3));
      const float so = fmaf(k0, qm4[j].x, fmaf(k1, qm4[j].y, fmaf(k2, qm4[j].z, k3 * qm4[j].w)));
      const float si = fmaf(k0, qn.x, fmaf(k1, qn.y, fmaf(k2, qn.z, k3 * qn.w)));
      if (j < 2) { po0 += so; pi0 += si; } else { po1 += so; pi1 += si; }
    }
    po0 += __shfl_xor(po0, 16, 64); po0 += __shfl_xor(po0, 32, 64);
    po1 += __shfl_xor(po1, 16, 64); po1 += __shfl_xor(po1, 32, 64);
    pi0 += __shfl_xor(pi0, 16, 64); pi0 += __shfl_xor(pi0, 32, 64);
    pi1 += __shfl_xor(pi1, 16, 64); pi1 += __shfl_xor(pi1, 32, 64);
    if (lk == 0) {
      const int h0 = w * 2, h1 = w * 2 + 1;
      osc [((size_t)(b * 8 + h0) * 128 + m) * 128 + ng] = po0 * inv_sqrt;
      osc [((size_t)(b * 8 + h1) * 128 + m) * 128 + ng] = po1 * inv_sqrt;
      iscT[((size_t)(b * 8 + h0) * 128 + m) * 128 + ng] = pi0 * inv_sqrt;
      iscT[((size_t)(b * 8 + h1) * 128 + m) * 128 + ng] = pi1 * inv_sqrt;
    }
  }
}

// ---------------------------------------------------------------------------
// message: softmaxes + gating. in-scores now read from the TRANSPOSED
// tensor iscT[b,h,m,n] (column gather, L2-resident) — the transpose killed
// kscore's scattered-write HBM amplification.
// ---------------------------------------------------------------------------
__global__ __launch_bounds__(128) void message_kernel(
    const float* __restrict__ osc, const float* __restrict__ iscT,
    const float* __restrict__ adjs, const int* __restrict__ mask,
    float* __restrict__ msg) {
  __shared__ float red[128];
  const int bhi = blockIdx.x;
  const int i = bhi & 127;
  const int bh = bhi >> 7;
  const int b = bhi >> 10;
  const int j = threadIdx.x;
  const bool mj = mask[b * 128 + j] != 0;

  const float so = mj ? osc[(size_t)bhi * 128 + j] : -INFINITY;
  const float si = mj ? iscT[((size_t)bh * 128 + j) * 128 + i] : -INFINITY;

  red[j] = so; __syncthreads();
  for (int s = 64; s > 0; s >>= 1) { if (j < s) red[j] = fmaxf(red[j], red[j + s]); __syncthreads(); }
  const float mo = red[0]; __syncthreads();
  const float eo = expf(so - mo);
  red[j] = eo; __syncthreads();
  for (int s = 64; s > 0; s >>= 1) { if (j < s) red[j] += red[j + s]; __syncthreads(); }
  const float zo = red[0]; __syncthreads();
  const float oa = eo / zo;

  red[j] = si; __syncthreads();
  for (int s = 64; s > 0; s >>= 1) { if (j < s) red[j] = fmaxf(red[j], red[j + s]); __syncthreads(); }
  const float mi = red[0]; __syncthreads();
  const float ei = expf(si - mi);
  red[j] = ei; __syncthreads();
  for (int s = 64; s > 0; s >>= 1) { if (j < s) red[j] += red[j + s]; __syncthreads(); }
  const float zi = red[0];
  const float ia = ei / zi;

  float val = oa + ia - ((i == j) ? oa : 0.0f);
  val *= adjs[((size_t)(b * 128 + i)) * 128 + j];
  msg[(size_t)bhi * 128 + j] = val;
}

// ---------------------------------------------------------------------------
// node_hidden (unchanged)
// ---------------------------------------------------------------------------
__global__ __launch_bounds__(256) void node_hidden_kernel(
    const float* __restrict__ msg, const float* __restrict__ v,
    float* __restrict__ nh) {
  __shared__ float Ms[32][129];
  __shared__ float Vs[128][33];
  const int blk = blockIdx.x;
  const int mblk = blk & 3;
  const int bh = blk >> 2;
  const int h = bh & 7;
  const int b = bh >> 3;
  const int t = threadIdx.x;

  {
    const int n = t & 127, r0 = t >> 7;
#pragma unroll
    for (int p = 0; p < 16; ++p) {
      const int r = r0 + p * 2;
      Ms[r][n] = msg[((size_t)bh * 128 + mblk * 32 + r) * 128 + n];
    }
  }
  {
    const int dk = t & 31, n0 = t >> 5;
#pragma unroll
    for (int p = 0; p < 16; ++p) {
      const int n = n0 + p * 8;
      Vs[n][dk] = v[((size_t)b * 128 + n) * 256 + h * 32 + dk];
    }
  }
  __syncthreads();

  const int dk = t & 31;
  const int mg = t >> 5;
  float acc[4] = {0.f, 0.f, 0.f, 0.f};
  for (int n = 0; n < 128; ++n) {
    const float vv = Vs[n][dk];
#pragma unroll
    for (int r = 0; r < 4; ++r) acc[r] = fmaf(Ms[mg + 8 * r][n], vv, acc[r]);
  }
#pragma unroll
  for (int r = 0; r < 4; ++r) {
    const int m = mblk * 32 + mg + 8 * r;
    nh[((size_t)b * 128 + m) * 256 + h * 32 + dk] = acc[r];
  }
}

// ---------------------------------------------------------------------------
// edge2 v2 — barrier-free main loop, LDS-free. out = bf16(kbf .* msg) @
// Weo^T + beo, kbf = stashed bf16 k in upper 512 B of each out row's slot.
// Fragments load directly global->reg (kbf scatter-free: 4 lanes x 16 B =
// 64 B line per row; msg gather is 64 B-contiguous over rows; weo is
// L2-resident). ONE barrier before the in-place epilogue: waves 2/3's
// output bytes alias the stash bytes other waves read.
// ---------------------------------------------------------------------------
__global__ __launch_bounds__(256) void edge2_kernel(
    float* edge, const float* __restrict__ msg,
    const unsigned short* __restrict__ weo, const float* __restrict__ beo) {
  const int nblk = blockIdx.x;          // 0..1
  const int bm = blockIdx.y;            // 0..1023
  const int b = bm >> 7;
  const int m = bm & 127;
  const int n0 = nblk * 64;
  const int t = threadIdx.x;
  const int l = t & 63;
  const int w = t >> 6;                 // wave -> out col group of 64
  const int lr = l & 15;
  const int lk = l >> 4;
  const unsigned short* kbf = (const unsigned short*)edge;
  const size_t g0 = (size_t)bm * 128 + n0;   // first global edge row

  floatx4 acc[4][4] = {};

#pragma unroll 2
  for (int c = 0; c < 8; ++c) {
    const int kk = c * 32;               // head c
    short8 a[4], bw[4];
#pragma unroll
    for (int i = 0; i < 4; ++i) {
      const int row = i * 16 + lr;
      const short8 kv = *(const short8*)&kbf[(g0 + row) * 512 + 256 + kk + lk * 8];
      const float sc = msg[(((size_t)(b * 8 + c) * 128 + m)) * 128 + n0 + row];
#pragma unroll
      for (int e = 0; e < 8; ++e)
        a[i][e] = (short)f2bf(bf2f((unsigned short)kv[e]) * sc);
    }
#pragma unroll
    for (int j = 0; j < 4; ++j)
      bw[j] = *(const short8*)&weo[(size_t)(w * 64 + j * 16 + lr) * 256 + kk + lk * 8];
#pragma unroll
    for (int i = 0; i < 4; ++i)
#pragma unroll
      for (int j = 0; j < 4; ++j)   // swapped operands -> lane holds 4 consecutive cols
        acc[i][j] = __builtin_amdgcn_mfma_f32_16x16x32_bf16(bw[j], a[i], acc[i][j], 0, 0, 0);
  }

  __syncthreads();   // all waves' stash reads retired before in-place stores

  // epilogue: lane holds OUT[row=i*16+lr][col=w*64+j*16+lk*4 .. +3] -> float4
  float4 bj[4];
#pragma unroll
  for (int j = 0; j < 4; ++j) bj[j] = *(const float4*)&beo[w * 64 + j * 16 + lk * 4];
  const size_t rowbase = g0 * 256;
#pragma unroll
  for (int i = 0; i < 4; ++i) {
    const size_t rb = rowbase + (size_t)(i * 16 + lr) * 256;
#pragma unroll
    for (int j = 0; j < 4; ++j) {
      float4 o;
      o.x = acc[i][j][0] + bj[j].x;
      o.y = acc[i][j][1] + bj[j].y;
      o.z = acc[i][j][2] + bj[j].z;
      o.w = acc[i][j][3] + bj[j].w;
      *(float4*)&edge[rb + w * 64 + j * 16 + lk * 4] = o;
    }
  }
}

// ---------------------------------------------------------------------------
extern "C" void kernel_launch(void* const* d_in, const int* in_sizes, int n_in,
                              void* d_out, int out_size, void* d_ws, size_t ws_size,
                              hipStream_t stream) {
  (void)in_sizes; (void)n_in; (void)out_size; (void)ws_size;
  const float* query_node = (const float*)d_in[0];
  const float* value_node = (const float*)d_in[1];
  const float* key_edge   = (const float*)d_in[2];
  const float* adj_matrix = (const float*)d_in[3];
  const int*   mask       = (const int*)d_in[4];
  const float* Wq  = (const float*)d_in[5];
  const float* bq  = (const float*)d_in[6];
  const float* Wk  = (const float*)d_in[7];
  const float* bk  = (const float*)d_in[8];
  const float* Wv  = (const float*)d_in[9];
  const float* bv  = (const float*)d_in[10];
  const float* Wno = (const float*)d_in[11];
  const float* bno = (const float*)d_in[12];
  const float* Weo = (const float*)d_in[13];
  const float* beo = (const float*)d_in[14];
  const float* lam = (const float*)d_in[15];

  float* out = (float*)d_out;
  float* node_out = out;                                  // [B,N,D]
  float* edge_out = out + (size_t)Bc * Nc * Dc;           // [B,N,N,D]; upper half
                                                          // of each row = bf16-k stash

  float* ws = (float*)d_ws;
  float* q    = ws; ws += (size_t)Bc * Nc * Dc;
  float* v    = ws; ws += (size_t)Bc * Nc * Dc;
  float* adjs = ws; ws += (size_t)Bc * Nc * Nc;
  float* osc  = ws; ws += (size_t)Bc * Hc * Nc * Nc;
  float* iscT = ws; ws += (size_t)Bc * Hc * Nc * Nc;
  float* msg  = ws; ws += (size_t)Bc * Hc * Nc * Nc;
  float* nh   = ws; ws += (size_t)Bc * Nc * Dc;
  unsigned short* wkbf  = (unsigned short*)ws; ws += 32768;   // 65536 bf16
  unsigned short* weobf = (unsigned short*)ws; ws += 32768;   // 65536 bf16

  // pre-cast weights to bf16 (MFMA kernel inputs)
  cast_bf16_kernel<<<dim3(64), 256, 0, stream>>>(Wk, wkbf, Dc * Dc);
  cast_bf16_kernel<<<dim3(64), 256, 0, stream>>>(Weo, weobf, Dc * Dc);
  // q, v projections (fp32, small)
  gemm_xwT_kernel<<<dim3(4, 16), 256, 0, stream>>>(query_node, Wq, bq, q, Bc * Nc);
  gemm_xwT_kernel<<<dim3(4, 16), 256, 0, stream>>>(value_node, Wv, bv, v, Bc * Nc);
  // adjacency softmax
  adj_softmax_kernel<<<dim3(Bc * Nc), 128, 0, stream>>>(adj_matrix, mask, lam, adjs);
  // k via MFMA (barrier-free) -> scores + bf16-k stash in edge_out upper halves
  kscore_kernel<<<dim3(2, 1024), 256, 0, stream>>>(key_edge, q, wkbf, bk, osc, iscT, edge_out);
  // softmaxes + message
  message_kernel<<<dim3(Bc * Hc * Nc), 128, 0, stream>>>(osc, iscT, adjs, mask, msg);
  // node hidden + node projection (fp32)
  node_hidden_kernel<<<dim3(Bc * Hc * 4), 256, 0, stream>>>(msg, v, nh);
  gemm_xwT_kernel<<<dim3(4, 16), 256, 0, stream>>>(nh, Wno, bno, node_out, Bc * Nc);
  // edge output: msg-scale stashed bf16 k, project with Weo (in-place safe)
  edge2_kernel<<<dim3(2, 1024), 256, 0, stream>>>(edge_out, msg, weobf, beo);
}